// Round 9
// baseline (1638.885 us; speedup 1.0000x reference)
//
#include <hip/hip_runtime.h>
#include <math.h>

#define N_NODES 100000
#define N_EDGES 3200000
#define B_GRAPHS 500
#define K_TOP 30
#define F_INN 128
#define H1C 64
#define NUM_CLASSES 18
#define XC 65               // H1 + 1
#define P_LEN (K_TOP * XC)  // 1950
#define C3_OUT 16
#define C3_K 97
#define C3_L 20
#define P2_L 10
#define C4_OUT 32
#define C4_K 5
#define C4_L 6
#define FC1_IN 192
#define FC1_OUT 128

#define BK_SHIFT 7
#define BK_NODES 128                               // nodes per bucket
#define NBKT ((N_NODES + BK_NODES - 1) / BK_NODES) // 782
#define BSTRIDE 5120                               // slots per bucket (mean 4092 + 16 sigma)
#define MS_EPT 16                                  // edges per thread in mscatter
#define MS_EPB (256 * MS_EPT)                      // 4096 edges per block

typedef __attribute__((ext_vector_type(8))) short bf16x8;
typedef __attribute__((ext_vector_type(4))) float f32x4;

// bf16 helpers
static __device__ __forceinline__ unsigned short f2bf(float f) {
    unsigned int u = __float_as_uint(f);
    u += 0x7FFFu + ((u >> 16) & 1u);   // round to nearest even
    return (unsigned short)(u >> 16);
}
static __device__ __forceinline__ float bfl(unsigned int u) {   // low bf16
    return __uint_as_float(u << 16);
}
static __device__ __forceinline__ float bfh(unsigned int u) {   // high bf16
    return __uint_as_float(u & 0xFFFF0000u);
}

// ------- multi-split scatter: ebkt[b*BSTRIDE + slot] = (row<<7 | col_local) -------
__global__ __launch_bounds__(256) void k_mscatter(const int* __restrict__ row,
                                                  const int* __restrict__ col,
                                                  int* __restrict__ gcur,
                                                  unsigned int* __restrict__ ebkt) {
    __shared__ int hist[NBKT];
    __shared__ int base[NBKT];
    int tid = threadIdx.x;
    for (int i = tid; i < NBKT; i += 256) hist[i] = 0;
    __syncthreads();
    unsigned int pk[MS_EPT];   // (bucket<<12) | rank, or sentinel
    unsigned int pay[MS_EPT];  // (row<<7) | col_local
    int e0 = blockIdx.x * MS_EPB;
#pragma unroll
    for (int j = 0; j < MS_EPT; ++j) {
        int e = e0 + j * 256 + tid;
        pk[j] = 0xFFFFFFFFu;
        if (e < N_EDGES) {
            int r = row[e], c = col[e];
            if (r != c) {
                int b = c >> BK_SHIFT;
                int rank = atomicAdd(&hist[b], 1);
                pk[j] = ((unsigned int)b << 12) | (unsigned int)rank;
                pay[j] = ((unsigned int)r << BK_SHIFT) | (unsigned int)(c & (BK_NODES - 1));
            }
        }
    }
    __syncthreads();
    for (int i = tid; i < NBKT; i += 256)
        base[i] = hist[i] ? (i * BSTRIDE + atomicAdd(&gcur[i], hist[i])) : 0;
    __syncthreads();
#pragma unroll
    for (int j = 0; j < MS_EPT; ++j) {
        if (pk[j] != 0xFFFFFFFFu) {
            int b = pk[j] >> 12;
            int rank = pk[j] & 0xFFF;
            ebkt[base[b] + rank] = pay[j];
        }
    }
}

// ------- per-bucket degree histogram -> dis -------
__global__ __launch_bounds__(256) void k_deg(const unsigned int* __restrict__ ebkt,
                                             const int* __restrict__ gcur,
                                             float* __restrict__ dis) {
    __shared__ int cnt[BK_NODES];
    int b = blockIdx.x, t = threadIdx.x;
    if (t < BK_NODES) cnt[t] = 0;
    __syncthreads();
    int lo = b * BSTRIDE, n = gcur[b];
    for (int i = t; i < n; i += 256)
        atomicAdd(&cnt[ebkt[lo + i] & (BK_NODES - 1)], 1);
    __syncthreads();
    int node = b * BK_NODES + t;
    if (t < BK_NODES && node < N_NODES)
        dis[node] = rsqrtf((float)cnt[t] + 1.0f);
}

// ---------------- xws = dis[r] * (x @ W1) via MFMA, bf16 CHANNEL-INTERLEAVED output ----------------
// ushort slot I(c) = ((c&31)<<1) | (c>>5): word w holds channels (w, w+32)
__global__ __launch_bounds__(256) void k_xw1(const float* __restrict__ x,
                                             const float* __restrict__ W1,
                                             const float* __restrict__ dis,
                                             unsigned short* __restrict__ xw) {
    __shared__ unsigned short w1s[16 * 64 * 8];   // 16 frags x 64 lanes x 8 bf16 = 16KB
    int tid = threadIdx.x;
    for (int idx = tid; idx < 16 * 64 * 8; idx += 256) {
        int f = idx >> 9;
        int l = (idx >> 3) & 63;
        int j = idx & 7;
        int kq = f >> 2, t4 = f & 3;
        int k = kq * 32 + ((l >> 4) << 3) + j;
        int n = t4 * 16 + (l & 15);
        w1s[idx] = f2bf(W1[k * H1C + n]);
    }
    __syncthreads();
    int wave = tid >> 6;
    int lane = tid & 63;
    int quad = lane >> 4;
    int m = lane & 15;
    int wrow0 = blockIdx.x * 64 + wave * 16;

    bf16x8 bw[16];
#pragma unroll
    for (int f = 0; f < 16; ++f)
        bw[f] = *(const bf16x8*)&w1s[(f * 64 + lane) * 8];

    f32x4 acc[4];
#pragma unroll
    for (int t = 0; t < 4; ++t) acc[t] = (f32x4){0.f, 0.f, 0.f, 0.f};

    int rowA = wrow0 + m;
    size_t ra = (size_t)(rowA < N_NODES ? rowA : N_NODES - 1);
#pragma unroll
    for (int kq = 0; kq < 4; ++kq) {
        const float* xp = x + ra * F_INN + kq * 32 + quad * 8;
        float4 f0 = ((const float4*)xp)[0];
        float4 f1 = ((const float4*)xp)[1];
        bf16x8 a;
        a[0] = (short)f2bf(f0.x); a[1] = (short)f2bf(f0.y);
        a[2] = (short)f2bf(f0.z); a[3] = (short)f2bf(f0.w);
        a[4] = (short)f2bf(f1.x); a[5] = (short)f2bf(f1.y);
        a[6] = (short)f2bf(f1.z); a[7] = (short)f2bf(f1.w);
#pragma unroll
        for (int t = 0; t < 4; ++t)
            acc[t] = __builtin_amdgcn_mfma_f32_16x16x32_bf16(a, bw[kq * 4 + t], acc[t], 0, 0, 0);
    }
#pragma unroll
    for (int r = 0; r < 4; ++r) {
        int rowD = wrow0 + quad * 4 + r;
        if (rowD < N_NODES) {
            float dsc = dis[rowD];
#pragma unroll
            for (int t = 0; t < 4; ++t) {
                int c = t * 16 + m;
                int I = ((c & 31) << 1) | (c >> 5);
                xw[(size_t)rowD * H1C + I] = f2bf(acc[t][r] * dsc);
            }
        }
    }
}

// ------- conv1: per-bucket LDS-tile aggregation from unordered bucket edge list -------
__global__ __launch_bounds__(256) void k_agg1b(const unsigned int* __restrict__ ebkt,
                                               const int* __restrict__ gcur,
                                               const unsigned short* __restrict__ xws,
                                               const float* __restrict__ dis,
                                               const float* __restrict__ b1,
                                               const float* __restrict__ W2,
                                               float* __restrict__ x1,
                                               float* __restrict__ xws2) {
    __shared__ float tile[BK_NODES * H1C];   // 32 KB, natural [node][ch]
    int b = blockIdx.x, tid = threadIdx.x;
    float4* tz = (float4*)tile;
    for (int i = tid; i < BK_NODES * H1C / 4; i += 256)
        tz[i] = make_float4(0.f, 0.f, 0.f, 0.f);
    __syncthreads();
    int lo = b * BSTRIDE;
    int cnt = gcur[b];
    int hw = tid >> 5;          // half-wave 0..7
    int l = tid & 31;
    const char* xb = (const char*)xws;
    int clamp = cnt > 0 ? cnt - 1 : 0;
    for (int bi = 0; bi < cnt; bi += 16) {
        int i0 = bi + hw;
        int i1 = bi + 8 + hw;
        int j0 = i0 <= clamp ? i0 : clamp;
        int j1 = i1 <= clamp ? i1 : clamp;
        unsigned int p0 = ebkt[lo + j0];
        unsigned int p1 = ebkt[lo + j1];
        unsigned int u0 = *(const unsigned int*)(xb + (p0 & ~127u) + l * 4);
        unsigned int u1 = *(const unsigned int*)(xb + (p1 & ~127u) + l * 4);
        if (i0 >= cnt) u0 = 0;   // adding 0.0f is harmless
        if (i1 >= cnt) u1 = 0;
        int c0 = (int)(p0 & 127u) * H1C;
        int c1 = (int)(p1 & 127u) * H1C;
        atomicAdd(&tile[c0 + l],      bfl(u0));   // bank = l%32, conflict-free
        atomicAdd(&tile[c0 + 32 + l], bfh(u0));
        atomicAdd(&tile[c1 + l],      bfl(u1));
        atomicAdd(&tile[c1 + 32 + l], bfh(u1));
    }
    __syncthreads();
    // epilogue: wave w handles nodes w*32..w*32+31; 64 lanes = 64 channels
    int wave = tid >> 6, lane = tid & 63;
    for (int q = 0; q < 32; ++q) {
        int cl = wave * 32 + q;
        int node = b * BK_NODES + cl;
        if (node >= N_NODES) break;
        float acc = tile[cl * H1C + lane];
        const unsigned int* rw = (const unsigned int*)(xb + ((size_t)node << 7));
        unsigned int sw = rw[lane & 31];
        float self = (lane < 32) ? bfl(sw) : bfh(sw);
        float d = dis[node];
        float r = tanhf(d * (acc + self) + b1[lane]);
        x1[(size_t)node * H1C + lane] = r;
        float s = r * W2[lane];
        s += __shfl_xor(s, 1); s += __shfl_xor(s, 2); s += __shfl_xor(s, 4);
        s += __shfl_xor(s, 8); s += __shfl_xor(s, 16); s += __shfl_xor(s, 32);
        if (lane == 0) xws2[node] = d * s;   // pre-scaled by dis
    }
}

// ------- conv2: per-bucket scalar LDS aggregation -------
__global__ __launch_bounds__(256) void k_agg2b(const unsigned int* __restrict__ ebkt,
                                               const int* __restrict__ gcur,
                                               const float* __restrict__ xws2,
                                               const float* __restrict__ dis,
                                               const float* __restrict__ b2,
                                               float* __restrict__ x2) {
    __shared__ float acc2[BK_NODES];
    int b = blockIdx.x, t = threadIdx.x;
    if (t < BK_NODES) acc2[t] = 0.f;
    __syncthreads();
    int lo = b * BSTRIDE, n = gcur[b];
    for (int i = t; i < n; i += 256) {
        unsigned int p = ebkt[lo + i];
        atomicAdd(&acc2[p & (BK_NODES - 1)], xws2[p >> BK_SHIFT]);
    }
    __syncthreads();
    int node = b * BK_NODES + t;
    if (t < BK_NODES && node < N_NODES)
        x2[node] = tanhf(dis[node] * (acc2[t] + xws2[node]) + b2[0]);
}

// ------- sort-pool: wave per graph, scores register-resident (cap 512 >> ~200) -------
__global__ __launch_bounds__(256) void k_pool(const int* __restrict__ batch,
                                              const float* __restrict__ x1,
                                              const float* __restrict__ x2,
                                              float* __restrict__ p) {
    int g = blockIdx.x * 4 + (threadIdx.x >> 6);
    int lane = threadIdx.x & 63;
    if (g >= B_GRAPHS) return;
    int lo = 0, hi = N_NODES;
    while (lo < hi) { int m = (lo + hi) >> 1; if (batch[m] < g) lo = m + 1; else hi = m; }
    int start = lo;
    hi = N_NODES;
    while (lo < hi) { int m = (lo + hi) >> 1; if (batch[m] < g + 1) lo = m + 1; else hi = m; }
    int end = lo;
    int count = end - start;
    unsigned long long k[8];
#pragma unroll
    for (int i = 0; i < 8; ++i) {
        int idx = start + i * 64 + lane;
        unsigned long long key = 0ULL;
        if (idx < end) {
            unsigned int bits = __float_as_uint(x2[idx]);
            unsigned int u = (bits & 0x80000000u) ? ~bits : (bits | 0x80000000u);
            key = ((unsigned long long)u << 32) | (unsigned int)(~(unsigned int)idx);
        }
        k[i] = key;
    }
    int kk = count < K_TOP ? count : K_TOP;
    for (int j = 0; j < kk; ++j) {
        unsigned long long best = k[0];
#pragma unroll
        for (int i = 1; i < 8; ++i) if (k[i] > best) best = k[i];
#pragma unroll
        for (int off = 32; off; off >>= 1) {
            unsigned long long o = __shfl_xor(best, off);
            if (o > best) best = o;
        }
        int node = (int)(~(unsigned int)(best & 0xFFFFFFFFULL));
#pragma unroll
        for (int i = 0; i < 8; ++i) if (k[i] == best) k[i] = 0ULL;
        size_t off0 = (size_t)g * P_LEN + (size_t)j * XC;
        p[off0 + lane] = x1[(size_t)node * H1C + lane];
        if (lane == 0) p[off0 + 64] = x2[node];
    }
}

// ---------------- head ----------------
__global__ __launch_bounds__(256) void k_head(const float* __restrict__ p,
                                              const float* __restrict__ w3, const float* __restrict__ b3,
                                              const float* __restrict__ w4, const float* __restrict__ b4,
                                              const float* __restrict__ fw1, const float* __restrict__ fb1,
                                              const float* __restrict__ fw2, const float* __restrict__ fb2,
                                              float* __restrict__ out) {
    __shared__ float ps[P_LEN];
    __shared__ float h1s[C3_OUT * C3_L];
    __shared__ float h2s[C3_OUT * P2_L];
    __shared__ float h3s[FC1_IN];
    __shared__ float lls[FC1_OUT];
    __shared__ float outs[NUM_CLASSES];
    int g = blockIdx.x, tid = threadIdx.x;
    for (int i = tid; i < P_LEN; i += 256) ps[i] = p[(size_t)g * P_LEN + i];
    __syncthreads();
    for (int o = tid; o < C3_OUT * C3_L; o += 256) {
        int oc = o / C3_L, pos = o % C3_L;
        float s = b3[oc];
        const float* w = w3 + oc * C3_K;
        int base = pos * C3_K;
        for (int k = 0; k < C3_K; ++k) s += ps[base + k] * w[k];
        h1s[o] = fmaxf(s, 0.0f);
    }
    __syncthreads();
    if (tid < C3_OUT * P2_L) {
        int oc = tid / P2_L, pos = tid % P2_L;
        h2s[tid] = fmaxf(h1s[oc * C3_L + 2 * pos], h1s[oc * C3_L + 2 * pos + 1]);
    }
    __syncthreads();
    if (tid < C4_OUT * C4_L) {
        int oc = tid / C4_L, pos = tid % C4_L;
        float s = b4[oc];
        for (int ic = 0; ic < C3_OUT; ++ic)
#pragma unroll
            for (int k = 0; k < C4_K; ++k)
                s += h2s[ic * P2_L + pos + k] * w4[oc * C3_OUT * C4_K + ic * C4_K + k];
        h3s[oc * C4_L + pos] = fmaxf(s, 0.0f);
    }
    __syncthreads();
    if (tid < FC1_OUT) {
        float s = fb1[tid];
        for (int i = 0; i < FC1_IN; ++i) s += h3s[i] * fw1[i * FC1_OUT + tid];
        float v = fmaxf(s, 0.0f);
        lls[tid] = v;
        out[2 * B_GRAPHS * NUM_CLASSES + (size_t)g * FC1_OUT + tid] = v;
    }
    __syncthreads();
    if (tid < NUM_CLASSES) {
        float s = fb2[tid];
        for (int j = 0; j < FC1_OUT; ++j) s += lls[j] * fw2[j * NUM_CLASSES + tid];
        outs[tid] = s;
        out[B_GRAPHS * NUM_CLASSES + (size_t)g * NUM_CLASSES + tid] = s;
    }
    __syncthreads();
    if (tid < NUM_CLASSES) {
        float m = -INFINITY;
        for (int k2 = 0; k2 < NUM_CLASSES; ++k2) m = fmaxf(m, outs[k2]);
        float se = 0.0f;
        for (int k2 = 0; k2 < NUM_CLASSES; ++k2) se += expf(outs[k2] - m);
        out[(size_t)g * NUM_CLASSES + tid] = outs[tid] - m - logf(se);
    }
}

extern "C" void kernel_launch(void* const* d_in, const int* in_sizes, int n_in,
                              void* d_out, int out_size, void* d_ws, size_t ws_size,
                              hipStream_t stream) {
    const float* x   = (const float*)d_in[0];
    const int*   ei  = (const int*)d_in[1];
    const int*   row = ei;
    const int*   col = ei + N_EDGES;
    const int*   bat = (const int*)d_in[2];
    const float* W1  = (const float*)d_in[4];
    const float* b1  = (const float*)d_in[5];
    const float* W2  = (const float*)d_in[6];
    const float* b2  = (const float*)d_in[7];
    const float* w3  = (const float*)d_in[8];
    const float* b3  = (const float*)d_in[9];
    const float* w4  = (const float*)d_in[10];
    const float* b4  = (const float*)d_in[11];
    const float* fw1 = (const float*)d_in[12];
    const float* fb1 = (const float*)d_in[13];
    const float* fw2 = (const float*)d_in[14];
    const float* fb2 = (const float*)d_in[15];

    char* wsb = (char*)d_ws;
    unsigned short* xws = (unsigned short*)wsb;       wsb += (size_t)N_NODES * H1C * 2;       // 12.8 MB bf16 interleaved
    float* x1     = (float*)wsb;                      wsb += (size_t)N_NODES * H1C * 4;       // 25.6 MB
    unsigned int* ebkt = (unsigned int*)wsb;          wsb += (size_t)NBKT * BSTRIDE * 4;      // 16.0 MB
    int*   gcur   = (int*)wsb;                        wsb += (size_t)NBKT * 4;
    float* dis    = (float*)wsb;                      wsb += (size_t)N_NODES * 4;
    float* xws2   = (float*)wsb;                      wsb += (size_t)N_NODES * 4;
    float* x2     = (float*)wsb;                      wsb += (size_t)N_NODES * 4;
    float* p      = (float*)wsb;                      wsb += (size_t)B_GRAPHS * P_LEN * 4;
    float* outp   = (float*)d_out;

    hipMemsetAsync(gcur, 0, (size_t)NBKT * 4, stream);
    hipMemsetAsync(p, 0, (size_t)B_GRAPHS * P_LEN * 4, stream);

    k_mscatter<<<(N_EDGES + MS_EPB - 1) / MS_EPB, 256, 0, stream>>>(row, col, gcur, ebkt);
    k_deg<<<NBKT, 256, 0, stream>>>(ebkt, gcur, dis);
    k_xw1<<<(N_NODES + 63) / 64, 256, 0, stream>>>(x, W1, dis, xws);
    k_agg1b<<<NBKT, 256, 0, stream>>>(ebkt, gcur, xws, dis, b1, W2, x1, xws2);
    k_agg2b<<<NBKT, 256, 0, stream>>>(ebkt, gcur, xws2, dis, b2, x2);
    k_pool<<<(B_GRAPHS + 3) / 4, 256, 0, stream>>>(bat, x1, x2, p);
    k_head<<<B_GRAPHS, 256, 0, stream>>>(p, w3, b3, w4, b4, fw1, fb1, fw2, fb2, outp);
}

// Round 10
// 368.267 us; speedup vs baseline: 4.4503x; 4.4503x over previous
//
#include <hip/hip_runtime.h>
#include <math.h>

#define N_NODES 100000
#define N_EDGES 3200000
#define B_GRAPHS 500
#define K_TOP 30
#define F_INN 128
#define H1C 64
#define NUM_CLASSES 18
#define XC 65               // H1 + 1
#define P_LEN (K_TOP * XC)  // 1950
#define C3_OUT 16
#define C3_K 97
#define C3_L 20
#define P2_L 10
#define C4_OUT 32
#define C4_K 5
#define C4_L 6
#define FC1_IN 192
#define FC1_OUT 128

#define BK_SHIFT 7
#define BK_NODES 128                               // nodes per bucket
#define NBKT ((N_NODES + BK_NODES - 1) / BK_NODES) // 782
#define BSTRIDE 5120                               // slots per bucket (mean 4092 + 16 sigma)
#define MS_EPT 16                                  // edges per thread in mscatter
#define MS_EPB (256 * MS_EPT)                      // 4096 edges per block

typedef __attribute__((ext_vector_type(8))) short bf16x8;
typedef __attribute__((ext_vector_type(4))) float f32x4;

// bf16 helpers
static __device__ __forceinline__ unsigned short f2bf(float f) {
    unsigned int u = __float_as_uint(f);
    u += 0x7FFFu + ((u >> 16) & 1u);   // round to nearest even
    return (unsigned short)(u >> 16);
}
static __device__ __forceinline__ float bfl(unsigned int u) {   // low bf16
    return __uint_as_float(u << 16);
}
static __device__ __forceinline__ float bfh(unsigned int u) {   // high bf16
    return __uint_as_float(u & 0xFFFF0000u);
}

// ------- multi-split scatter: ebkt[b*BSTRIDE + slot] = (row<<7 | col_local) -------
__global__ __launch_bounds__(256) void k_mscatter(const int* __restrict__ row,
                                                  const int* __restrict__ col,
                                                  int* __restrict__ gcur,
                                                  unsigned int* __restrict__ ebkt) {
    __shared__ int hist[NBKT];
    __shared__ int base[NBKT];
    int tid = threadIdx.x;
    for (int i = tid; i < NBKT; i += 256) hist[i] = 0;
    __syncthreads();
    unsigned int pk[MS_EPT];   // (bucket<<12) | rank, or sentinel
    unsigned int pay[MS_EPT];  // (row<<7) | col_local
    int e0 = blockIdx.x * MS_EPB;
#pragma unroll
    for (int j = 0; j < MS_EPT; ++j) {
        int e = e0 + j * 256 + tid;
        pk[j] = 0xFFFFFFFFu;
        if (e < N_EDGES) {
            int r = row[e], c = col[e];
            if (r != c) {
                int b = c >> BK_SHIFT;
                int rank = atomicAdd(&hist[b], 1);
                pk[j] = ((unsigned int)b << 12) | (unsigned int)rank;
                pay[j] = ((unsigned int)r << BK_SHIFT) | (unsigned int)(c & (BK_NODES - 1));
            }
        }
    }
    __syncthreads();
    for (int i = tid; i < NBKT; i += 256)
        base[i] = hist[i] ? (i * BSTRIDE + atomicAdd(&gcur[i], hist[i])) : 0;
    __syncthreads();
#pragma unroll
    for (int j = 0; j < MS_EPT; ++j) {
        if (pk[j] != 0xFFFFFFFFu) {
            int b = pk[j] >> 12;
            int rank = pk[j] & 0xFFF;
            ebkt[base[b] + rank] = pay[j];
        }
    }
}

// ------- merged CSR build: count -> scan -> dis/rowse -> rank-scatter erow (byte offsets) -------
__global__ __launch_bounds__(256) void k_csr(const unsigned int* __restrict__ ebkt,
                                             const int* __restrict__ gcur,
                                             float* __restrict__ dis,
                                             int2* __restrict__ rowse,
                                             int* __restrict__ erow) {
    __shared__ int cnt[BK_NODES];
    __shared__ int s[256];
    __shared__ int cur[BK_NODES];
    int b = blockIdx.x, t = threadIdx.x;
    if (t < BK_NODES) cnt[t] = 0;
    __syncthreads();
    int lo = b * BSTRIDE;
    int hi = lo + gcur[b];
    for (int i = lo + t; i < hi; i += 256)
        atomicAdd(&cnt[ebkt[i] & (BK_NODES - 1)], 1);
    __syncthreads();
    int v = (t < BK_NODES) ? cnt[t] : 0;
    s[t] = v;
    __syncthreads();
    for (int off = 1; off < BK_NODES; off <<= 1) {
        int add = (t >= off) ? s[t - off] : 0;
        __syncthreads();
        s[t] += add;
        __syncthreads();
    }
    int ex = s[t] - v;
    if (t < BK_NODES) {
        int node = b * BK_NODES + t;
        if (node < N_NODES) {
            dis[node] = rsqrtf((float)v + 1.0f);
            rowse[node] = make_int2(lo + ex, lo + ex + v);
        }
        cur[t] = lo + ex;
    }
    __syncthreads();
    for (int i = lo + t; i < hi; i += 256) {
        unsigned int pk = ebkt[i];
        int cl = pk & (BK_NODES - 1);
        int slot = atomicAdd(&cur[cl], 1);
        erow[slot] = (int)((pk >> BK_SHIFT) << 7);   // byte offset into bf16 rows (128B)
    }
}

// ---------------- xws = dis[r] * (x @ W1) via MFMA, bf16 output ----------------
// block: 4 waves x 16 rows = 64 rows. W1 staged to LDS in B-fragment order (bf16).
__global__ __launch_bounds__(256) void k_xw1(const float* __restrict__ x,
                                             const float* __restrict__ W1,
                                             const float* __restrict__ dis,
                                             unsigned short* __restrict__ xw) {
    __shared__ unsigned short w1s[16 * 64 * 8];   // 16 frags x 64 lanes x 8 bf16 = 16KB
    int tid = threadIdx.x;
    // stage W1 (128x64 fp32) -> bf16 fragments: frag f=(kq*4+t), lane l, elem j
    // holds W1[kq*32 + (l>>4)*8 + j][t*16 + (l&15)]
    for (int idx = tid; idx < 16 * 64 * 8; idx += 256) {
        int f = idx >> 9;
        int l = (idx >> 3) & 63;
        int j = idx & 7;
        int kq = f >> 2, t4 = f & 3;
        int k = kq * 32 + ((l >> 4) << 3) + j;
        int n = t4 * 16 + (l & 15);
        w1s[idx] = f2bf(W1[k * H1C + n]);
    }
    __syncthreads();
    int wave = tid >> 6;
    int lane = tid & 63;
    int quad = lane >> 4;
    int m = lane & 15;
    int wrow0 = blockIdx.x * 64 + wave * 16;

    bf16x8 bw[16];
#pragma unroll
    for (int f = 0; f < 16; ++f)
        bw[f] = *(const bf16x8*)&w1s[(f * 64 + lane) * 8];

    f32x4 acc[4];
#pragma unroll
    for (int t = 0; t < 4; ++t) acc[t] = (f32x4){0.f, 0.f, 0.f, 0.f};

    int rowA = wrow0 + m;
    size_t ra = (size_t)(rowA < N_NODES ? rowA : N_NODES - 1);
#pragma unroll
    for (int kq = 0; kq < 4; ++kq) {
        const float* xp = x + ra * F_INN + kq * 32 + quad * 8;
        float4 f0 = ((const float4*)xp)[0];
        float4 f1 = ((const float4*)xp)[1];
        bf16x8 a;
        a[0] = (short)f2bf(f0.x); a[1] = (short)f2bf(f0.y);
        a[2] = (short)f2bf(f0.z); a[3] = (short)f2bf(f0.w);
        a[4] = (short)f2bf(f1.x); a[5] = (short)f2bf(f1.y);
        a[6] = (short)f2bf(f1.z); a[7] = (short)f2bf(f1.w);
#pragma unroll
        for (int t = 0; t < 4; ++t)
            acc[t] = __builtin_amdgcn_mfma_f32_16x16x32_bf16(a, bw[kq * 4 + t], acc[t], 0, 0, 0);
    }
#pragma unroll
    for (int r = 0; r < 4; ++r) {
        int rowD = wrow0 + quad * 4 + r;
        if (rowD < N_NODES) {
            float dsc = dis[rowD];
#pragma unroll
            for (int t = 0; t < 4; ++t)
                xw[(size_t)rowD * H1C + t * 16 + m] = f2bf(acc[t][r] * dsc);
        }
    }
}

// ------- conv1 gather: 8 lanes/edge, uint4 bf16, 32 edges/iter (2nd half wave-uniform) -------
__global__ __launch_bounds__(256) void k_agg1f(const int2* __restrict__ rowse,
                                               const int* __restrict__ erow,
                                               const unsigned short* __restrict__ xws,
                                               const float* __restrict__ dis,
                                               const float* __restrict__ b1,
                                               const float* __restrict__ W2,
                                               float* __restrict__ x1,
                                               float* __restrict__ xws2) {
    int wid = blockIdx.x * 4 + (threadIdx.x >> 6);
    int lane = threadIdx.x & 63;
    if (wid >= N_NODES) return;
    int grp = lane >> 3;   // 0..7
    int sub = lane & 7;    // 0..7
    int2 se = rowse[wid];
    int base = se.x, endp = se.y;
    const char* xb = (const char*)xws;
    const int ZR = N_NODES << 7;   // zero row pad (L1-cached)
    float acc[8] = {0.f, 0.f, 0.f, 0.f, 0.f, 0.f, 0.f, 0.f};
    for (int e0 = base; e0 < endp; e0 += 32) {
        int i0 = e0 + grp;
        int i1 = e0 + 8 + grp;
        int o0 = (i0 < endp) ? erow[i0] : ZR;
        int o1 = (i1 < endp) ? erow[i1] : ZR;
        uint4 a = ((const uint4*)(xb + o0))[sub];
        uint4 bq = ((const uint4*)(xb + o1))[sub];
        acc[0] += bfl(a.x) + bfl(bq.x);
        acc[1] += bfh(a.x) + bfh(bq.x);
        acc[2] += bfl(a.y) + bfl(bq.y);
        acc[3] += bfh(a.y) + bfh(bq.y);
        acc[4] += bfl(a.z) + bfl(bq.z);
        acc[5] += bfh(a.z) + bfh(bq.z);
        acc[6] += bfl(a.w) + bfl(bq.w);
        acc[7] += bfh(a.w) + bfh(bq.w);
        if (e0 + 16 < endp) {   // wave-uniform: endp is per-node
            int i2 = e0 + 16 + grp;
            int i3 = e0 + 24 + grp;
            int o2 = (i2 < endp) ? erow[i2] : ZR;
            int o3 = (i3 < endp) ? erow[i3] : ZR;
            uint4 c = ((const uint4*)(xb + o2))[sub];
            uint4 dq = ((const uint4*)(xb + o3))[sub];
            acc[0] += bfl(c.x) + bfl(dq.x);
            acc[1] += bfh(c.x) + bfh(dq.x);
            acc[2] += bfl(c.y) + bfl(dq.y);
            acc[3] += bfh(c.y) + bfh(dq.y);
            acc[4] += bfl(c.z) + bfl(dq.z);
            acc[5] += bfh(c.z) + bfh(dq.z);
            acc[6] += bfl(c.w) + bfl(dq.w);
            acc[7] += bfh(c.w) + bfh(dq.w);
        }
    }
#pragma unroll
    for (int i = 0; i < 8; ++i) {
        acc[i] += __shfl_xor(acc[i], 8);
        acc[i] += __shfl_xor(acc[i], 16);
        acc[i] += __shfl_xor(acc[i], 32);
    }
    if (grp == 0) {   // lanes 0..7 hold channels [8*sub, 8*sub+8)
        float d = dis[wid];
        uint4 ow = ((const uint4*)(xb + ((size_t)wid << 7)))[sub];
        float self[8] = {bfl(ow.x), bfh(ow.x), bfl(ow.y), bfh(ow.y),
                         bfl(ow.z), bfh(ow.z), bfl(ow.w), bfh(ow.w)};
        float4 bb0 = ((const float4*)b1)[sub * 2];
        float4 bb1 = ((const float4*)b1)[sub * 2 + 1];
        float r[8];
        r[0] = tanhf(d * (acc[0] + self[0]) + bb0.x);
        r[1] = tanhf(d * (acc[1] + self[1]) + bb0.y);
        r[2] = tanhf(d * (acc[2] + self[2]) + bb0.z);
        r[3] = tanhf(d * (acc[3] + self[3]) + bb0.w);
        r[4] = tanhf(d * (acc[4] + self[4]) + bb1.x);
        r[5] = tanhf(d * (acc[5] + self[5]) + bb1.y);
        r[6] = tanhf(d * (acc[6] + self[6]) + bb1.z);
        r[7] = tanhf(d * (acc[7] + self[7]) + bb1.w);
        ((float4*)(x1 + (size_t)wid * H1C))[sub * 2] = make_float4(r[0], r[1], r[2], r[3]);
        ((float4*)(x1 + (size_t)wid * H1C))[sub * 2 + 1] = make_float4(r[4], r[5], r[6], r[7]);
        float4 w20 = ((const float4*)W2)[sub * 2];
        float4 w21 = ((const float4*)W2)[sub * 2 + 1];
        float s = r[0] * w20.x + r[1] * w20.y + r[2] * w20.z + r[3] * w20.w +
                  r[4] * w21.x + r[5] * w21.y + r[6] * w21.z + r[7] * w21.w;
        s += __shfl_xor(s, 1);
        s += __shfl_xor(s, 2);
        s += __shfl_xor(s, 4);
        if (sub == 0) xws2[wid] = d * s;   // pre-scaled by dis
    }
}

// ------- conv2 gather (scalar, pre-scaled) + tanh (wave per node) -------
__global__ __launch_bounds__(256) void k_agg2f(const int2* __restrict__ rowse,
                                               const int* __restrict__ erow,
                                               const float* __restrict__ xws2,
                                               const float* __restrict__ dis,
                                               const float* __restrict__ b2,
                                               float* __restrict__ x2) {
    int wid = blockIdx.x * 4 + (threadIdx.x >> 6);
    int lane = threadIdx.x & 63;
    if (wid >= N_NODES) return;
    int2 se = rowse[wid];
    float acc = 0.0f;
    for (int idx = se.x + lane; idx < se.y; idx += 64)
        acc += xws2[erow[idx] >> 7];
    for (int off = 32; off; off >>= 1) acc += __shfl_xor(acc, off);
    if (lane == 0)
        x2[wid] = tanhf(dis[wid] * (acc + xws2[wid]) + b2[0]);
}

// ------- sort-pool: wave per graph, scores register-resident (cap 512 >> ~200) -------
__global__ __launch_bounds__(256) void k_pool(const int* __restrict__ batch,
                                              const float* __restrict__ x1,
                                              const float* __restrict__ x2,
                                              float* __restrict__ p) {
    int g = blockIdx.x * 4 + (threadIdx.x >> 6);
    int lane = threadIdx.x & 63;
    if (g >= B_GRAPHS) return;
    int lo = 0, hi = N_NODES;
    while (lo < hi) { int m = (lo + hi) >> 1; if (batch[m] < g) lo = m + 1; else hi = m; }
    int start = lo;
    hi = N_NODES;
    while (lo < hi) { int m = (lo + hi) >> 1; if (batch[m] < g + 1) lo = m + 1; else hi = m; }
    int end = lo;
    int count = end - start;
    unsigned long long k[8];
#pragma unroll
    for (int i = 0; i < 8; ++i) {
        int idx = start + i * 64 + lane;
        unsigned long long key = 0ULL;
        if (idx < end) {
            unsigned int bits = __float_as_uint(x2[idx]);
            unsigned int u = (bits & 0x80000000u) ? ~bits : (bits | 0x80000000u);
            key = ((unsigned long long)u << 32) | (unsigned int)(~(unsigned int)idx);
        }
        k[i] = key;
    }
    int kk = count < K_TOP ? count : K_TOP;
    for (int j = 0; j < kk; ++j) {
        unsigned long long best = k[0];
#pragma unroll
        for (int i = 1; i < 8; ++i) if (k[i] > best) best = k[i];
#pragma unroll
        for (int off = 32; off; off >>= 1) {
            unsigned long long o = __shfl_xor(best, off);
            if (o > best) best = o;
        }
        int node = (int)(~(unsigned int)(best & 0xFFFFFFFFULL));
#pragma unroll
        for (int i = 0; i < 8; ++i) if (k[i] == best) k[i] = 0ULL;
        size_t off0 = (size_t)g * P_LEN + (size_t)j * XC;
        p[off0 + lane] = x1[(size_t)node * H1C + lane];
        if (lane == 0) p[off0 + 64] = x2[node];
    }
}

// ---------------- head ----------------
__global__ __launch_bounds__(256) void k_head(const float* __restrict__ p,
                                              const float* __restrict__ w3, const float* __restrict__ b3,
                                              const float* __restrict__ w4, const float* __restrict__ b4,
                                              const float* __restrict__ fw1, const float* __restrict__ fb1,
                                              const float* __restrict__ fw2, const float* __restrict__ fb2,
                                              float* __restrict__ out) {
    __shared__ float ps[P_LEN];
    __shared__ float h1s[C3_OUT * C3_L];
    __shared__ float h2s[C3_OUT * P2_L];
    __shared__ float h3s[FC1_IN];
    __shared__ float lls[FC1_OUT];
    __shared__ float outs[NUM_CLASSES];
    int g = blockIdx.x, tid = threadIdx.x;
    for (int i = tid; i < P_LEN; i += 256) ps[i] = p[(size_t)g * P_LEN + i];
    __syncthreads();
    for (int o = tid; o < C3_OUT * C3_L; o += 256) {
        int oc = o / C3_L, pos = o % C3_L;
        float s = b3[oc];
        const float* w = w3 + oc * C3_K;
        int base = pos * C3_K;
        for (int k = 0; k < C3_K; ++k) s += ps[base + k] * w[k];
        h1s[o] = fmaxf(s, 0.0f);
    }
    __syncthreads();
    if (tid < C3_OUT * P2_L) {
        int oc = tid / P2_L, pos = tid % P2_L;
        h2s[tid] = fmaxf(h1s[oc * C3_L + 2 * pos], h1s[oc * C3_L + 2 * pos + 1]);
    }
    __syncthreads();
    if (tid < C4_OUT * C4_L) {
        int oc = tid / C4_L, pos = tid % C4_L;
        float s = b4[oc];
        for (int ic = 0; ic < C3_OUT; ++ic)
#pragma unroll
            for (int k = 0; k < C4_K; ++k)
                s += h2s[ic * P2_L + pos + k] * w4[oc * C3_OUT * C4_K + ic * C4_K + k];
        h3s[oc * C4_L + pos] = fmaxf(s, 0.0f);
    }
    __syncthreads();
    if (tid < FC1_OUT) {
        float s = fb1[tid];
        for (int i = 0; i < FC1_IN; ++i) s += h3s[i] * fw1[i * FC1_OUT + tid];
        float v = fmaxf(s, 0.0f);
        lls[tid] = v;
        out[2 * B_GRAPHS * NUM_CLASSES + (size_t)g * FC1_OUT + tid] = v;
    }
    __syncthreads();
    if (tid < NUM_CLASSES) {
        float s = fb2[tid];
        for (int j = 0; j < FC1_OUT; ++j) s += lls[j] * fw2[j * NUM_CLASSES + tid];
        outs[tid] = s;
        out[B_GRAPHS * NUM_CLASSES + (size_t)g * NUM_CLASSES + tid] = s;
    }
    __syncthreads();
    if (tid < NUM_CLASSES) {
        float m = -INFINITY;
        for (int k2 = 0; k2 < NUM_CLASSES; ++k2) m = fmaxf(m, outs[k2]);
        float se = 0.0f;
        for (int k2 = 0; k2 < NUM_CLASSES; ++k2) se += expf(outs[k2] - m);
        out[(size_t)g * NUM_CLASSES + tid] = outs[tid] - m - logf(se);
    }
}

extern "C" void kernel_launch(void* const* d_in, const int* in_sizes, int n_in,
                              void* d_out, int out_size, void* d_ws, size_t ws_size,
                              hipStream_t stream) {
    const float* x   = (const float*)d_in[0];
    const int*   ei  = (const int*)d_in[1];
    const int*   row = ei;
    const int*   col = ei + N_EDGES;
    const int*   bat = (const int*)d_in[2];
    const float* W1  = (const float*)d_in[4];
    const float* b1  = (const float*)d_in[5];
    const float* W2  = (const float*)d_in[6];
    const float* b2  = (const float*)d_in[7];
    const float* w3  = (const float*)d_in[8];
    const float* b3  = (const float*)d_in[9];
    const float* w4  = (const float*)d_in[10];
    const float* b4  = (const float*)d_in[11];
    const float* fw1 = (const float*)d_in[12];
    const float* fb1 = (const float*)d_in[13];
    const float* fw2 = (const float*)d_in[14];
    const float* fb2 = (const float*)d_in[15];

    char* wsb = (char*)d_ws;
    unsigned short* xws = (unsigned short*)wsb;       wsb += (size_t)(N_NODES + 1) * H1C * 2; // 12.8 MB (+zero row)
    float* x1     = (float*)wsb;                      wsb += (size_t)N_NODES * H1C * 4;       // 25.6 MB
    int*   erow   = (int*)wsb;                        wsb += (size_t)NBKT * BSTRIDE * 4;      // 16.0 MB
    // ebkt aliases x1 (16.0 MB <= 25.6 MB): consumed by k_csr before k_agg1f writes x1
    unsigned int* ebkt = (unsigned int*)x1;
    int*   gcur   = (int*)wsb;                        wsb += (size_t)NBKT * 4;
    int2*  rowse  = (int2*)wsb;                       wsb += (size_t)N_NODES * 8;
    float* dis    = (float*)wsb;                      wsb += (size_t)N_NODES * 4;
    float* xws2   = (float*)wsb;                      wsb += (size_t)N_NODES * 4;
    float* x2     = (float*)wsb;                      wsb += (size_t)N_NODES * 4;
    float* p      = (float*)wsb;                      wsb += (size_t)B_GRAPHS * P_LEN * 4;
    float* outp   = (float*)d_out;

    hipMemsetAsync(gcur, 0, (size_t)NBKT * 4, stream);
    hipMemsetAsync(p, 0, (size_t)B_GRAPHS * P_LEN * 4, stream);
    hipMemsetAsync(xws + (size_t)N_NODES * H1C, 0, H1C * 2, stream);  // zero row for padding

    k_mscatter<<<(N_EDGES + MS_EPB - 1) / MS_EPB, 256, 0, stream>>>(row, col, gcur, ebkt);
    k_csr<<<NBKT, 256, 0, stream>>>(ebkt, gcur, dis, rowse, erow);
    k_xw1<<<(N_NODES + 63) / 64, 256, 0, stream>>>(x, W1, dis, xws);
    k_agg1f<<<(N_NODES + 3) / 4, 256, 0, stream>>>(rowse, erow, xws, dis, b1, W2, x1, xws2);
    k_agg2f<<<(N_NODES + 3) / 4, 256, 0, stream>>>(rowse, erow, xws2, dis, b2, x2);
    k_pool<<<(B_GRAPHS + 3) / 4, 256, 0, stream>>>(bat, x1, x2, p);
    k_head<<<B_GRAPHS, 256, 0, stream>>>(p, w3, b3, w4, b4, fw1, fb1, fw2, fb2, outp);
}

// Round 11
// 343.310 us; speedup vs baseline: 4.7738x; 1.0727x over previous
//
#include <hip/hip_runtime.h>
#include <math.h>

#define N_NODES 100000
#define N_EDGES 3200000
#define B_GRAPHS 500
#define K_TOP 30
#define F_INN 128
#define H1C 64
#define NUM_CLASSES 18
#define XC 65               // H1 + 1
#define P_LEN (K_TOP * XC)  // 1950
#define C3_OUT 16
#define C3_K 97
#define C3_L 20
#define P2_L 10
#define C4_OUT 32
#define C4_K 5
#define C4_L 6
#define FC1_IN 192
#define FC1_OUT 128

#define BK_SHIFT 7
#define BK_NODES 128                               // nodes per bucket
#define NBKT ((N_NODES + BK_NODES - 1) / BK_NODES) // 782
#define BSTRIDE 5120                               // slots per bucket (mean 4092 + 16 sigma)
#define MS_EPT 16                                  // edges per thread in mscatter
#define MS_EPB (256 * MS_EPT)                      // 4096 edges per block

typedef __attribute__((ext_vector_type(8))) short bf16x8;
typedef __attribute__((ext_vector_type(4))) float f32x4;

// bf16 helpers
static __device__ __forceinline__ unsigned short f2bf(float f) {
    unsigned int u = __float_as_uint(f);
    u += 0x7FFFu + ((u >> 16) & 1u);   // round to nearest even
    return (unsigned short)(u >> 16);
}
static __device__ __forceinline__ float bfl(unsigned int u) {   // low bf16
    return __uint_as_float(u << 16);
}
static __device__ __forceinline__ float bfh(unsigned int u) {   // high bf16
    return __uint_as_float(u & 0xFFFF0000u);
}

// ------- multi-split scatter: ebkt[b*BSTRIDE + slot] = (row<<7 | col_local) -------
__global__ __launch_bounds__(256) void k_mscatter(const int* __restrict__ row,
                                                  const int* __restrict__ col,
                                                  int* __restrict__ gcur,
                                                  unsigned int* __restrict__ ebkt) {
    __shared__ int hist[NBKT];
    __shared__ int base[NBKT];
    int tid = threadIdx.x;
    for (int i = tid; i < NBKT; i += 256) hist[i] = 0;
    __syncthreads();
    unsigned int pk[MS_EPT];   // (bucket<<12) | rank, or sentinel
    unsigned int pay[MS_EPT];  // (row<<7) | col_local
    int e0 = blockIdx.x * MS_EPB;
#pragma unroll
    for (int j = 0; j < MS_EPT; ++j) {
        int e = e0 + j * 256 + tid;
        pk[j] = 0xFFFFFFFFu;
        if (e < N_EDGES) {
            int r = row[e], c = col[e];
            if (r != c) {
                int b = c >> BK_SHIFT;
                int rank = atomicAdd(&hist[b], 1);
                pk[j] = ((unsigned int)b << 12) | (unsigned int)rank;
                pay[j] = ((unsigned int)r << BK_SHIFT) | (unsigned int)(c & (BK_NODES - 1));
            }
        }
    }
    __syncthreads();
    for (int i = tid; i < NBKT; i += 256)
        base[i] = hist[i] ? (i * BSTRIDE + atomicAdd(&gcur[i], hist[i])) : 0;
    __syncthreads();
#pragma unroll
    for (int j = 0; j < MS_EPT; ++j) {
        if (pk[j] != 0xFFFFFFFFu) {
            int b = pk[j] >> 12;
            int rank = pk[j] & 0xFFF;
            ebkt[base[b] + rank] = pay[j];
        }
    }
}

// ------- merged CSR build: count -> scan -> dis/rowse -> rank-scatter erow (byte offsets) -------
__global__ __launch_bounds__(256) void k_csr(const unsigned int* __restrict__ ebkt,
                                             const int* __restrict__ gcur,
                                             float* __restrict__ dis,
                                             int2* __restrict__ rowse,
                                             int* __restrict__ erow) {
    __shared__ int cnt[BK_NODES];
    __shared__ int s[256];
    __shared__ int cur[BK_NODES];
    int b = blockIdx.x, t = threadIdx.x;
    if (t < BK_NODES) cnt[t] = 0;
    __syncthreads();
    int lo = b * BSTRIDE;
    int hi = lo + gcur[b];
    for (int i = lo + t; i < hi; i += 256)
        atomicAdd(&cnt[ebkt[i] & (BK_NODES - 1)], 1);
    __syncthreads();
    int v = (t < BK_NODES) ? cnt[t] : 0;
    s[t] = v;
    __syncthreads();
    for (int off = 1; off < BK_NODES; off <<= 1) {
        int add = (t >= off) ? s[t - off] : 0;
        __syncthreads();
        s[t] += add;
        __syncthreads();
    }
    int ex = s[t] - v;
    if (t < BK_NODES) {
        int node = b * BK_NODES + t;
        if (node < N_NODES) {
            dis[node] = rsqrtf((float)v + 1.0f);
            rowse[node] = make_int2(lo + ex, lo + ex + v);
        }
        cur[t] = lo + ex;
    }
    __syncthreads();
    for (int i = lo + t; i < hi; i += 256) {
        unsigned int pk = ebkt[i];
        int cl = pk & (BK_NODES - 1);
        int slot = atomicAdd(&cur[cl], 1);
        erow[slot] = (int)((pk >> BK_SHIFT) << 7);   // byte offset into bf16 rows (128B)
    }
}

// ---------------- xws = dis[r] * (x @ W1) via MFMA, bf16 output ----------------
// block: 4 waves x 16 rows = 64 rows. W1 staged to LDS in B-fragment order (bf16).
// block 0 also zeroes the padding row N_NODES (replaces a memset dispatch).
__global__ __launch_bounds__(256) void k_xw1(const float* __restrict__ x,
                                             const float* __restrict__ W1,
                                             const float* __restrict__ dis,
                                             unsigned short* __restrict__ xw) {
    __shared__ unsigned short w1s[16 * 64 * 8];   // 16 frags x 64 lanes x 8 bf16 = 16KB
    int tid = threadIdx.x;
    if (blockIdx.x == 0 && tid < 32)
        ((unsigned int*)(xw + (size_t)N_NODES * H1C))[tid] = 0;   // zero pad row
    for (int idx = tid; idx < 16 * 64 * 8; idx += 256) {
        int f = idx >> 9;
        int l = (idx >> 3) & 63;
        int j = idx & 7;
        int kq = f >> 2, t4 = f & 3;
        int k = kq * 32 + ((l >> 4) << 3) + j;
        int n = t4 * 16 + (l & 15);
        w1s[idx] = f2bf(W1[k * H1C + n]);
    }
    __syncthreads();
    int wave = tid >> 6;
    int lane = tid & 63;
    int quad = lane >> 4;
    int m = lane & 15;
    int wrow0 = blockIdx.x * 64 + wave * 16;

    bf16x8 bw[16];
#pragma unroll
    for (int f = 0; f < 16; ++f)
        bw[f] = *(const bf16x8*)&w1s[(f * 64 + lane) * 8];

    f32x4 acc[4];
#pragma unroll
    for (int t = 0; t < 4; ++t) acc[t] = (f32x4){0.f, 0.f, 0.f, 0.f};

    int rowA = wrow0 + m;
    size_t ra = (size_t)(rowA < N_NODES ? rowA : N_NODES - 1);
#pragma unroll
    for (int kq = 0; kq < 4; ++kq) {
        const float* xp = x + ra * F_INN + kq * 32 + quad * 8;
        float4 f0 = ((const float4*)xp)[0];
        float4 f1 = ((const float4*)xp)[1];
        bf16x8 a;
        a[0] = (short)f2bf(f0.x); a[1] = (short)f2bf(f0.y);
        a[2] = (short)f2bf(f0.z); a[3] = (short)f2bf(f0.w);
        a[4] = (short)f2bf(f1.x); a[5] = (short)f2bf(f1.y);
        a[6] = (short)f2bf(f1.z); a[7] = (short)f2bf(f1.w);
#pragma unroll
        for (int t = 0; t < 4; ++t)
            acc[t] = __builtin_amdgcn_mfma_f32_16x16x32_bf16(a, bw[kq * 4 + t], acc[t], 0, 0, 0);
    }
#pragma unroll
    for (int r = 0; r < 4; ++r) {
        int rowD = wrow0 + quad * 4 + r;
        if (rowD < N_NODES) {
            float dsc = dis[rowD];
#pragma unroll
            for (int t = 0; t < 4; ++t)
                xw[(size_t)rowD * H1C + t * 16 + m] = f2bf(acc[t][r] * dsc);
        }
    }
}

// ------- conv1 gather: 8 lanes/edge, uint4 bf16, 16 edges/iter (proven R8 form) -------
__global__ __launch_bounds__(256) void k_agg1f(const int2* __restrict__ rowse,
                                               const int* __restrict__ erow,
                                               const unsigned short* __restrict__ xws,
                                               const float* __restrict__ dis,
                                               const float* __restrict__ b1,
                                               const float* __restrict__ W2,
                                               float* __restrict__ x1,
                                               float* __restrict__ xws2) {
    int wid = blockIdx.x * 4 + (threadIdx.x >> 6);
    int lane = threadIdx.x & 63;
    if (wid >= N_NODES) return;
    int grp = lane >> 3;   // 0..7
    int sub = lane & 7;    // 0..7
    int2 se = rowse[wid];
    int base = se.x, endp = se.y;
    const char* xb = (const char*)xws;
    const int ZR = N_NODES << 7;   // zero row pad (L1-cached)
    float acc[8] = {0.f, 0.f, 0.f, 0.f, 0.f, 0.f, 0.f, 0.f};
    for (int e0 = base; e0 < endp; e0 += 16) {
        int i0 = e0 + grp;
        int i1 = e0 + 8 + grp;
        int o0 = (i0 < endp) ? erow[i0] : ZR;
        int o1 = (i1 < endp) ? erow[i1] : ZR;
        uint4 a = ((const uint4*)(xb + o0))[sub];
        uint4 bq = ((const uint4*)(xb + o1))[sub];
        acc[0] += bfl(a.x) + bfl(bq.x);
        acc[1] += bfh(a.x) + bfh(bq.x);
        acc[2] += bfl(a.y) + bfl(bq.y);
        acc[3] += bfh(a.y) + bfh(bq.y);
        acc[4] += bfl(a.z) + bfl(bq.z);
        acc[5] += bfh(a.z) + bfh(bq.z);
        acc[6] += bfl(a.w) + bfl(bq.w);
        acc[7] += bfh(a.w) + bfh(bq.w);
    }
#pragma unroll
    for (int i = 0; i < 8; ++i) {
        acc[i] += __shfl_xor(acc[i], 8);
        acc[i] += __shfl_xor(acc[i], 16);
        acc[i] += __shfl_xor(acc[i], 32);
    }
    if (grp == 0) {   // lanes 0..7 hold channels [8*sub, 8*sub+8)
        float d = dis[wid];
        uint4 ow = ((const uint4*)(xb + ((size_t)wid << 7)))[sub];
        float self[8] = {bfl(ow.x), bfh(ow.x), bfl(ow.y), bfh(ow.y),
                         bfl(ow.z), bfh(ow.z), bfl(ow.w), bfh(ow.w)};
        float4 bb0 = ((const float4*)b1)[sub * 2];
        float4 bb1 = ((const float4*)b1)[sub * 2 + 1];
        float r[8];
        r[0] = tanhf(d * (acc[0] + self[0]) + bb0.x);
        r[1] = tanhf(d * (acc[1] + self[1]) + bb0.y);
        r[2] = tanhf(d * (acc[2] + self[2]) + bb0.z);
        r[3] = tanhf(d * (acc[3] + self[3]) + bb0.w);
        r[4] = tanhf(d * (acc[4] + self[4]) + bb1.x);
        r[5] = tanhf(d * (acc[5] + self[5]) + bb1.y);
        r[6] = tanhf(d * (acc[6] + self[6]) + bb1.z);
        r[7] = tanhf(d * (acc[7] + self[7]) + bb1.w);
        ((float4*)(x1 + (size_t)wid * H1C))[sub * 2] = make_float4(r[0], r[1], r[2], r[3]);
        ((float4*)(x1 + (size_t)wid * H1C))[sub * 2 + 1] = make_float4(r[4], r[5], r[6], r[7]);
        float4 w20 = ((const float4*)W2)[sub * 2];
        float4 w21 = ((const float4*)W2)[sub * 2 + 1];
        float s = r[0] * w20.x + r[1] * w20.y + r[2] * w20.z + r[3] * w20.w +
                  r[4] * w21.x + r[5] * w21.y + r[6] * w21.z + r[7] * w21.w;
        s += __shfl_xor(s, 1);
        s += __shfl_xor(s, 2);
        s += __shfl_xor(s, 4);
        if (sub == 0) xws2[wid] = d * s;   // pre-scaled by dis
    }
}

// ------- conv2 gather (scalar, pre-scaled) + tanh (wave per node) -------
__global__ __launch_bounds__(256) void k_agg2f(const int2* __restrict__ rowse,
                                               const int* __restrict__ erow,
                                               const float* __restrict__ xws2,
                                               const float* __restrict__ dis,
                                               const float* __restrict__ b2,
                                               float* __restrict__ x2) {
    int wid = blockIdx.x * 4 + (threadIdx.x >> 6);
    int lane = threadIdx.x & 63;
    if (wid >= N_NODES) return;
    int2 se = rowse[wid];
    float acc = 0.0f;
    for (int idx = se.x + lane; idx < se.y; idx += 64)
        acc += xws2[erow[idx] >> 7];
    for (int off = 32; off; off >>= 1) acc += __shfl_xor(acc, off);
    if (lane == 0)
        x2[wid] = tanhf(dis[wid] * (acc + xws2[wid]) + b2[0]);
}

// ------- fused sort-pool + head: one block per graph, p lives in LDS -------
__global__ __launch_bounds__(256) void k_poolhead(const int* __restrict__ batch,
                                                  const float* __restrict__ x1,
                                                  const float* __restrict__ x2,
                                                  const float* __restrict__ w3, const float* __restrict__ b3,
                                                  const float* __restrict__ w4, const float* __restrict__ b4,
                                                  const float* __restrict__ fw1, const float* __restrict__ fb1,
                                                  const float* __restrict__ fw2, const float* __restrict__ fb2,
                                                  float* __restrict__ out) {
    __shared__ float x2s[512];
    __shared__ int sel[K_TOP];
    __shared__ float ps[P_LEN];
    __shared__ float h1s[C3_OUT * C3_L];
    __shared__ float h2s[C3_OUT * P2_L];
    __shared__ float h3s[FC1_IN];
    __shared__ float lls[FC1_OUT];
    __shared__ float outs[NUM_CLASSES];
    int g = blockIdx.x, tid = threadIdx.x;
    // binary search for [start,end) — redundant per thread, broadcast loads
    int lo = 0, hi = N_NODES;
    while (lo < hi) { int m = (lo + hi) >> 1; if (batch[m] < g) lo = m + 1; else hi = m; }
    int start = lo;
    hi = N_NODES;
    while (lo < hi) { int m = (lo + hi) >> 1; if (batch[m] < g + 1) lo = m + 1; else hi = m; }
    int end = lo;
    int count = end - start;
    if (count > 512) count = 512;   // cap (impossible for this input: mean 200, sigma 14)
    // stage x2 for this graph into LDS
    for (int i = tid; i < count; i += 256) x2s[i] = x2[start + i];
    __syncthreads();
    int wave = tid >> 6, lane = tid & 63;
    // selection: wave 0 only, scores register-resident
    if (wave == 0) {
        unsigned long long k[8];
#pragma unroll
        for (int i = 0; i < 8; ++i) {
            int idx = i * 64 + lane;
            unsigned long long key = 0ULL;
            if (idx < count) {
                unsigned int bits = __float_as_uint(x2s[idx]);
                unsigned int u = (bits & 0x80000000u) ? ~bits : (bits | 0x80000000u);
                key = ((unsigned long long)u << 32) | (unsigned int)(~(unsigned int)(start + idx));
            }
            k[i] = key;
        }
        int kk = count < K_TOP ? count : K_TOP;
        for (int j = 0; j < kk; ++j) {
            unsigned long long best = k[0];
#pragma unroll
            for (int i = 1; i < 8; ++i) if (k[i] > best) best = k[i];
#pragma unroll
            for (int off = 32; off; off >>= 1) {
                unsigned long long o = __shfl_xor(best, off);
                if (o > best) best = o;
            }
            int node = (int)(~(unsigned int)(best & 0xFFFFFFFFULL));
#pragma unroll
            for (int i = 0; i < 8; ++i) if (k[i] == best) k[i] = 0ULL;
            if (lane == 0) sel[j] = node;
        }
        if (lane >= kk && lane < K_TOP) sel[lane] = -1;
    }
    __syncthreads();
    // gather p-tile into LDS
    for (int t = tid; t < P_LEN; t += 256) {
        int j = t / XC, c = t - j * XC;
        int node = sel[j];
        float v = 0.0f;
        if (node >= 0) v = (c < H1C) ? x1[(size_t)node * H1C + c] : x2s[node - start];
        ps[t] = v;
    }
    __syncthreads();
    // head
    for (int o = tid; o < C3_OUT * C3_L; o += 256) {
        int oc = o / C3_L, pos = o % C3_L;
        float s = b3[oc];
        const float* w = w3 + oc * C3_K;
        int base = pos * C3_K;
        for (int k = 0; k < C3_K; ++k) s += ps[base + k] * w[k];
        h1s[o] = fmaxf(s, 0.0f);
    }
    __syncthreads();
    if (tid < C3_OUT * P2_L) {
        int oc = tid / P2_L, pos = tid % P2_L;
        h2s[tid] = fmaxf(h1s[oc * C3_L + 2 * pos], h1s[oc * C3_L + 2 * pos + 1]);
    }
    __syncthreads();
    if (tid < C4_OUT * C4_L) {
        int oc = tid / C4_L, pos = tid % C4_L;
        float s = b4[oc];
        for (int ic = 0; ic < C3_OUT; ++ic)
#pragma unroll
            for (int k = 0; k < C4_K; ++k)
                s += h2s[ic * P2_L + pos + k] * w4[oc * C3_OUT * C4_K + ic * C4_K + k];
        h3s[oc * C4_L + pos] = fmaxf(s, 0.0f);
    }
    __syncthreads();
    if (tid < FC1_OUT) {
        float s = fb1[tid];
        for (int i = 0; i < FC1_IN; ++i) s += h3s[i] * fw1[i * FC1_OUT + tid];
        float v = fmaxf(s, 0.0f);
        lls[tid] = v;
        out[2 * B_GRAPHS * NUM_CLASSES + (size_t)g * FC1_OUT + tid] = v;
    }
    __syncthreads();
    if (tid < NUM_CLASSES) {
        float s = fb2[tid];
        for (int j = 0; j < FC1_OUT; ++j) s += lls[j] * fw2[j * NUM_CLASSES + tid];
        outs[tid] = s;
        out[B_GRAPHS * NUM_CLASSES + (size_t)g * NUM_CLASSES + tid] = s;
    }
    __syncthreads();
    if (tid < NUM_CLASSES) {
        float m = -INFINITY;
        for (int k2 = 0; k2 < NUM_CLASSES; ++k2) m = fmaxf(m, outs[k2]);
        float se = 0.0f;
        for (int k2 = 0; k2 < NUM_CLASSES; ++k2) se += expf(outs[k2] - m);
        out[(size_t)g * NUM_CLASSES + tid] = outs[tid] - m - logf(se);
    }
}

extern "C" void kernel_launch(void* const* d_in, const int* in_sizes, int n_in,
                              void* d_out, int out_size, void* d_ws, size_t ws_size,
                              hipStream_t stream) {
    const float* x   = (const float*)d_in[0];
    const int*   ei  = (const int*)d_in[1];
    const int*   row = ei;
    const int*   col = ei + N_EDGES;
    const int*   bat = (const int*)d_in[2];
    const float* W1  = (const float*)d_in[4];
    const float* b1  = (const float*)d_in[5];
    const float* W2  = (const float*)d_in[6];
    const float* b2  = (const float*)d_in[7];
    const float* w3  = (const float*)d_in[8];
    const float* b3  = (const float*)d_in[9];
    const float* w4  = (const float*)d_in[10];
    const float* b4  = (const float*)d_in[11];
    const float* fw1 = (const float*)d_in[12];
    const float* fb1 = (const float*)d_in[13];
    const float* fw2 = (const float*)d_in[14];
    const float* fb2 = (const float*)d_in[15];

    char* wsb = (char*)d_ws;
    unsigned short* xws = (unsigned short*)wsb;       wsb += (size_t)(N_NODES + 1) * H1C * 2; // 12.8 MB (+zero row)
    float* x1     = (float*)wsb;                      wsb += (size_t)N_NODES * H1C * 4;       // 25.6 MB
    int*   erow   = (int*)wsb;                        wsb += (size_t)NBKT * BSTRIDE * 4;      // 16.0 MB
    // ebkt aliases x1 (16.0 MB <= 25.6 MB): consumed by k_csr before k_agg1f writes x1
    unsigned int* ebkt = (unsigned int*)x1;
    int*   gcur   = (int*)wsb;                        wsb += (size_t)NBKT * 4;
    int2*  rowse  = (int2*)wsb;                       wsb += (size_t)N_NODES * 8;
    float* dis    = (float*)wsb;                      wsb += (size_t)N_NODES * 4;
    float* xws2   = (float*)wsb;                      wsb += (size_t)N_NODES * 4;
    float* x2     = (float*)wsb;                      wsb += (size_t)N_NODES * 4;
    float* outp   = (float*)d_out;

    hipMemsetAsync(gcur, 0, (size_t)NBKT * 4, stream);

    k_mscatter<<<(N_EDGES + MS_EPB - 1) / MS_EPB, 256, 0, stream>>>(row, col, gcur, ebkt);
    k_csr<<<NBKT, 256, 0, stream>>>(ebkt, gcur, dis, rowse, erow);
    k_xw1<<<(N_NODES + 63) / 64, 256, 0, stream>>>(x, W1, dis, xws);
    k_agg1f<<<(N_NODES + 3) / 4, 256, 0, stream>>>(rowse, erow, xws, dis, b1, W2, x1, xws2);
    k_agg2f<<<(N_NODES + 3) / 4, 256, 0, stream>>>(rowse, erow, xws2, dis, b2, x2);
    k_poolhead<<<B_GRAPHS, 256, 0, stream>>>(bat, x1, x2, w3, b3, w4, b4, fw1, fb1, fw2, fb2, outp);
}

// Round 12
// 340.231 us; speedup vs baseline: 4.8170x; 1.0091x over previous
//
#include <hip/hip_runtime.h>
#include <math.h>

#define N_NODES 100000
#define N_EDGES 3200000
#define B_GRAPHS 500
#define K_TOP 30
#define F_INN 128
#define H1C 64
#define NUM_CLASSES 18
#define XC 65               // H1 + 1
#define P_LEN (K_TOP * XC)  // 1950
#define C3_OUT 16
#define C3_K 97
#define C3_L 20
#define P2_L 10
#define C4_OUT 32
#define C4_K 5
#define C4_L 6
#define FC1_IN 192
#define FC1_OUT 128

#define BK_SHIFT 7
#define BK_NODES 128                               // nodes per bucket
#define NBKT ((N_NODES + BK_NODES - 1) / BK_NODES) // 782
#define BSTRIDE 5120                               // slots per bucket (mean 4092 + 16 sigma)
#define MS_EPT 16                                  // edges per thread in mscatter
#define MS_EPB (256 * MS_EPT)                      // 4096 edges per block

typedef __attribute__((ext_vector_type(8))) short bf16x8;
typedef __attribute__((ext_vector_type(4))) float f32x4;

// bf16 helpers
static __device__ __forceinline__ unsigned short f2bf(float f) {
    unsigned int u = __float_as_uint(f);
    u += 0x7FFFu + ((u >> 16) & 1u);   // round to nearest even
    return (unsigned short)(u >> 16);
}
static __device__ __forceinline__ float bfl(unsigned int u) {   // low bf16
    return __uint_as_float(u << 16);
}
static __device__ __forceinline__ float bfh(unsigned int u) {   // high bf16
    return __uint_as_float(u & 0xFFFF0000u);
}

// ------- multi-split scatter: ebkt[b*BSTRIDE + slot] = (row<<7 | col_local) -------
__global__ __launch_bounds__(256) void k_mscatter(const int* __restrict__ row,
                                                  const int* __restrict__ col,
                                                  int* __restrict__ gcur,
                                                  unsigned int* __restrict__ ebkt) {
    __shared__ int hist[NBKT];
    __shared__ int base[NBKT];
    int tid = threadIdx.x;
    for (int i = tid; i < NBKT; i += 256) hist[i] = 0;
    __syncthreads();
    unsigned int pk[MS_EPT];   // (bucket<<12) | rank, or sentinel
    unsigned int pay[MS_EPT];  // (row<<7) | col_local
    int e0 = blockIdx.x * MS_EPB;
#pragma unroll
    for (int j = 0; j < MS_EPT; ++j) {
        int e = e0 + j * 256 + tid;
        pk[j] = 0xFFFFFFFFu;
        if (e < N_EDGES) {
            int r = row[e], c = col[e];
            if (r != c) {
                int b = c >> BK_SHIFT;
                int rank = atomicAdd(&hist[b], 1);
                pk[j] = ((unsigned int)b << 12) | (unsigned int)rank;
                pay[j] = ((unsigned int)r << BK_SHIFT) | (unsigned int)(c & (BK_NODES - 1));
            }
        }
    }
    __syncthreads();
    for (int i = tid; i < NBKT; i += 256)
        base[i] = hist[i] ? (i * BSTRIDE + atomicAdd(&gcur[i], hist[i])) : 0;
    __syncthreads();
#pragma unroll
    for (int j = 0; j < MS_EPT; ++j) {
        if (pk[j] != 0xFFFFFFFFu) {
            int b = pk[j] >> 12;
            int rank = pk[j] & 0xFFF;
            ebkt[base[b] + rank] = pay[j];
        }
    }
}

// ------- merged CSR build: count -> scan -> dis/rowse -> rank-scatter erow (byte offsets) -------
__global__ __launch_bounds__(256) void k_csr(const unsigned int* __restrict__ ebkt,
                                             const int* __restrict__ gcur,
                                             float* __restrict__ dis,
                                             int2* __restrict__ rowse,
                                             int* __restrict__ erow) {
    __shared__ int cnt[BK_NODES];
    __shared__ int s[256];
    __shared__ int cur[BK_NODES];
    int b = blockIdx.x, t = threadIdx.x;
    if (t < BK_NODES) cnt[t] = 0;
    __syncthreads();
    int lo = b * BSTRIDE;
    int hi = lo + gcur[b];
    for (int i = lo + t; i < hi; i += 256)
        atomicAdd(&cnt[ebkt[i] & (BK_NODES - 1)], 1);
    __syncthreads();
    int v = (t < BK_NODES) ? cnt[t] : 0;
    s[t] = v;
    __syncthreads();
    for (int off = 1; off < BK_NODES; off <<= 1) {
        int add = (t >= off) ? s[t - off] : 0;
        __syncthreads();
        s[t] += add;
        __syncthreads();
    }
    int ex = s[t] - v;
    if (t < BK_NODES) {
        int node = b * BK_NODES + t;
        if (node < N_NODES) {
            dis[node] = rsqrtf((float)v + 1.0f);
            rowse[node] = make_int2(lo + ex, lo + ex + v);
        }
        cur[t] = lo + ex;
    }
    __syncthreads();
    for (int i = lo + t; i < hi; i += 256) {
        unsigned int pk = ebkt[i];
        int cl = pk & (BK_NODES - 1);
        int slot = atomicAdd(&cur[cl], 1);
        erow[slot] = (int)((pk >> BK_SHIFT) << 7);   // byte offset into bf16 rows (128B)
    }
}

// ---------------- xws = dis[r] * (x @ W1) via MFMA, bf16 output ----------------
// block: 4 waves x 16 rows = 64 rows. W1 staged to LDS in B-fragment order (bf16).
// block 0 also zeroes the padding row N_NODES (replaces a memset dispatch).
__global__ __launch_bounds__(256) void k_xw1(const float* __restrict__ x,
                                             const float* __restrict__ W1,
                                             const float* __restrict__ dis,
                                             unsigned short* __restrict__ xw) {
    __shared__ unsigned short w1s[16 * 64 * 8];   // 16 frags x 64 lanes x 8 bf16 = 16KB
    int tid = threadIdx.x;
    if (blockIdx.x == 0 && tid < 32)
        ((unsigned int*)(xw + (size_t)N_NODES * H1C))[tid] = 0;   // zero pad row
    for (int idx = tid; idx < 16 * 64 * 8; idx += 256) {
        int f = idx >> 9;
        int l = (idx >> 3) & 63;
        int j = idx & 7;
        int kq = f >> 2, t4 = f & 3;
        int k = kq * 32 + ((l >> 4) << 3) + j;
        int n = t4 * 16 + (l & 15);
        w1s[idx] = f2bf(W1[k * H1C + n]);
    }
    __syncthreads();
    int wave = tid >> 6;
    int lane = tid & 63;
    int quad = lane >> 4;
    int m = lane & 15;
    int wrow0 = blockIdx.x * 64 + wave * 16;

    bf16x8 bw[16];
#pragma unroll
    for (int f = 0; f < 16; ++f)
        bw[f] = *(const bf16x8*)&w1s[(f * 64 + lane) * 8];

    f32x4 acc[4];
#pragma unroll
    for (int t = 0; t < 4; ++t) acc[t] = (f32x4){0.f, 0.f, 0.f, 0.f};

    int rowA = wrow0 + m;
    size_t ra = (size_t)(rowA < N_NODES ? rowA : N_NODES - 1);
#pragma unroll
    for (int kq = 0; kq < 4; ++kq) {
        const float* xp = x + ra * F_INN + kq * 32 + quad * 8;
        float4 f0 = ((const float4*)xp)[0];
        float4 f1 = ((const float4*)xp)[1];
        bf16x8 a;
        a[0] = (short)f2bf(f0.x); a[1] = (short)f2bf(f0.y);
        a[2] = (short)f2bf(f0.z); a[3] = (short)f2bf(f0.w);
        a[4] = (short)f2bf(f1.x); a[5] = (short)f2bf(f1.y);
        a[6] = (short)f2bf(f1.z); a[7] = (short)f2bf(f1.w);
#pragma unroll
        for (int t = 0; t < 4; ++t)
            acc[t] = __builtin_amdgcn_mfma_f32_16x16x32_bf16(a, bw[kq * 4 + t], acc[t], 0, 0, 0);
    }
#pragma unroll
    for (int r = 0; r < 4; ++r) {
        int rowD = wrow0 + quad * 4 + r;
        if (rowD < N_NODES) {
            float dsc = dis[rowD];
#pragma unroll
            for (int t = 0; t < 4; ++t)
                xw[(size_t)rowD * H1C + t * 16 + m] = f2bf(acc[t][r] * dsc);
        }
    }
}

// ------- conv1 gather: 8 lanes/edge, uint4 bf16, 16 edges/iter (proven R8 form) -------
__global__ __launch_bounds__(256) void k_agg1f(const int2* __restrict__ rowse,
                                               const int* __restrict__ erow,
                                               const unsigned short* __restrict__ xws,
                                               const float* __restrict__ dis,
                                               const float* __restrict__ b1,
                                               const float* __restrict__ W2,
                                               float* __restrict__ x1,
                                               float* __restrict__ xws2) {
    int wid = blockIdx.x * 4 + (threadIdx.x >> 6);
    int lane = threadIdx.x & 63;
    if (wid >= N_NODES) return;
    int grp = lane >> 3;   // 0..7
    int sub = lane & 7;    // 0..7
    int2 se = rowse[wid];
    int base = se.x, endp = se.y;
    const char* xb = (const char*)xws;
    const int ZR = N_NODES << 7;   // zero row pad (L1-cached)
    float acc[8] = {0.f, 0.f, 0.f, 0.f, 0.f, 0.f, 0.f, 0.f};
    for (int e0 = base; e0 < endp; e0 += 16) {
        int i0 = e0 + grp;
        int i1 = e0 + 8 + grp;
        int o0 = (i0 < endp) ? erow[i0] : ZR;
        int o1 = (i1 < endp) ? erow[i1] : ZR;
        uint4 a = ((const uint4*)(xb + o0))[sub];
        uint4 bq = ((const uint4*)(xb + o1))[sub];
        acc[0] += bfl(a.x) + bfl(bq.x);
        acc[1] += bfh(a.x) + bfh(bq.x);
        acc[2] += bfl(a.y) + bfl(bq.y);
        acc[3] += bfh(a.y) + bfh(bq.y);
        acc[4] += bfl(a.z) + bfl(bq.z);
        acc[5] += bfh(a.z) + bfh(bq.z);
        acc[6] += bfl(a.w) + bfl(bq.w);
        acc[7] += bfh(a.w) + bfh(bq.w);
    }
#pragma unroll
    for (int i = 0; i < 8; ++i) {
        acc[i] += __shfl_xor(acc[i], 8);
        acc[i] += __shfl_xor(acc[i], 16);
        acc[i] += __shfl_xor(acc[i], 32);
    }
    if (grp == 0) {   // lanes 0..7 hold channels [8*sub, 8*sub+8)
        float d = dis[wid];
        uint4 ow = ((const uint4*)(xb + ((size_t)wid << 7)))[sub];
        float self[8] = {bfl(ow.x), bfh(ow.x), bfl(ow.y), bfh(ow.y),
                         bfl(ow.z), bfh(ow.z), bfl(ow.w), bfh(ow.w)};
        float4 bb0 = ((const float4*)b1)[sub * 2];
        float4 bb1 = ((const float4*)b1)[sub * 2 + 1];
        float r[8];
        r[0] = tanhf(d * (acc[0] + self[0]) + bb0.x);
        r[1] = tanhf(d * (acc[1] + self[1]) + bb0.y);
        r[2] = tanhf(d * (acc[2] + self[2]) + bb0.z);
        r[3] = tanhf(d * (acc[3] + self[3]) + bb0.w);
        r[4] = tanhf(d * (acc[4] + self[4]) + bb1.x);
        r[5] = tanhf(d * (acc[5] + self[5]) + bb1.y);
        r[6] = tanhf(d * (acc[6] + self[6]) + bb1.z);
        r[7] = tanhf(d * (acc[7] + self[7]) + bb1.w);
        ((float4*)(x1 + (size_t)wid * H1C))[sub * 2] = make_float4(r[0], r[1], r[2], r[3]);
        ((float4*)(x1 + (size_t)wid * H1C))[sub * 2 + 1] = make_float4(r[4], r[5], r[6], r[7]);
        float4 w20 = ((const float4*)W2)[sub * 2];
        float4 w21 = ((const float4*)W2)[sub * 2 + 1];
        float s = r[0] * w20.x + r[1] * w20.y + r[2] * w20.z + r[3] * w20.w +
                  r[4] * w21.x + r[5] * w21.y + r[6] * w21.z + r[7] * w21.w;
        s += __shfl_xor(s, 1);
        s += __shfl_xor(s, 2);
        s += __shfl_xor(s, 4);
        if (sub == 0) xws2[wid] = d * s;   // pre-scaled by dis
    }
}

// ------- fused conv2 + sort-pool + head: one block per graph -------
__global__ __launch_bounds__(256) void k_poolhead(const int* __restrict__ batch,
                                                  const float* __restrict__ x1,
                                                  const int2* __restrict__ rowse,
                                                  const int* __restrict__ erow,
                                                  const float* __restrict__ xws2,
                                                  const float* __restrict__ dis,
                                                  const float* __restrict__ b2,
                                                  const float* __restrict__ w3, const float* __restrict__ b3,
                                                  const float* __restrict__ w4, const float* __restrict__ b4,
                                                  const float* __restrict__ fw1, const float* __restrict__ fb1,
                                                  const float* __restrict__ fw2, const float* __restrict__ fb2,
                                                  float* __restrict__ out) {
    __shared__ float x2s[512];
    __shared__ int sel[K_TOP];
    __shared__ float ps[P_LEN];
    __shared__ float h1s[C3_OUT * C3_L];
    __shared__ float h2s[C3_OUT * P2_L];
    __shared__ float h3s[FC1_IN];
    __shared__ float lls[FC1_OUT];
    __shared__ float outs[NUM_CLASSES];
    int g = blockIdx.x, tid = threadIdx.x;
    // binary search for [start,end) — redundant per thread, broadcast loads
    int lo = 0, hi = N_NODES;
    while (lo < hi) { int m = (lo + hi) >> 1; if (batch[m] < g) lo = m + 1; else hi = m; }
    int start = lo;
    hi = N_NODES;
    while (lo < hi) { int m = (lo + hi) >> 1; if (batch[m] < g + 1) lo = m + 1; else hi = m; }
    int end = lo;
    int count = end - start;
    if (count > 512) count = 512;   // cap (impossible for this input: mean 200, sigma 14)
    // conv2 for this graph's nodes, into LDS
    float b2v = b2[0];
    for (int t = tid; t < count; t += 256) {
        int node = start + t;
        int2 se = rowse[node];
        float acc = 0.0f;
        for (int idx = se.x; idx < se.y; ++idx)
            acc += xws2[erow[idx] >> 7];
        x2s[t] = tanhf(dis[node] * (acc + xws2[node]) + b2v);
    }
    __syncthreads();
    int wave = tid >> 6, lane = tid & 63;
    // selection: wave 0 only, scores register-resident
    if (wave == 0) {
        unsigned long long k[8];
#pragma unroll
        for (int i = 0; i < 8; ++i) {
            int idx = i * 64 + lane;
            unsigned long long key = 0ULL;
            if (idx < count) {
                unsigned int bits = __float_as_uint(x2s[idx]);
                unsigned int u = (bits & 0x80000000u) ? ~bits : (bits | 0x80000000u);
                key = ((unsigned long long)u << 32) | (unsigned int)(~(unsigned int)(start + idx));
            }
            k[i] = key;
        }
        int kk = count < K_TOP ? count : K_TOP;
        for (int j = 0; j < kk; ++j) {
            unsigned long long best = k[0];
#pragma unroll
            for (int i = 1; i < 8; ++i) if (k[i] > best) best = k[i];
#pragma unroll
            for (int off = 32; off; off >>= 1) {
                unsigned long long o = __shfl_xor(best, off);
                if (o > best) best = o;
            }
            int node = (int)(~(unsigned int)(best & 0xFFFFFFFFULL));
#pragma unroll
            for (int i = 0; i < 8; ++i) if (k[i] == best) k[i] = 0ULL;
            if (lane == 0) sel[j] = node;
        }
        if (lane >= kk && lane < K_TOP) sel[lane] = -1;
    }
    __syncthreads();
    // gather p-tile into LDS
    for (int t = tid; t < P_LEN; t += 256) {
        int j = t / XC, c = t - j * XC;
        int node = sel[j];
        float v = 0.0f;
        if (node >= 0) v = (c < H1C) ? x1[(size_t)node * H1C + c] : x2s[node - start];
        ps[t] = v;
    }
    __syncthreads();
    // head
    for (int o = tid; o < C3_OUT * C3_L; o += 256) {
        int oc = o / C3_L, pos = o % C3_L;
        float s = b3[oc];
        const float* w = w3 + oc * C3_K;
        int base = pos * C3_K;
        for (int k = 0; k < C3_K; ++k) s += ps[base + k] * w[k];
        h1s[o] = fmaxf(s, 0.0f);
    }
    __syncthreads();
    if (tid < C3_OUT * P2_L) {
        int oc = tid / P2_L, pos = tid % P2_L;
        h2s[tid] = fmaxf(h1s[oc * C3_L + 2 * pos], h1s[oc * C3_L + 2 * pos + 1]);
    }
    __syncthreads();
    if (tid < C4_OUT * C4_L) {
        int oc = tid / C4_L, pos = tid % C4_L;
        float s = b4[oc];
        for (int ic = 0; ic < C3_OUT; ++ic)
#pragma unroll
            for (int k = 0; k < C4_K; ++k)
                s += h2s[ic * P2_L + pos + k] * w4[oc * C3_OUT * C4_K + ic * C4_K + k];
        h3s[oc * C4_L + pos] = fmaxf(s, 0.0f);
    }
    __syncthreads();
    if (tid < FC1_OUT) {
        float s = fb1[tid];
        for (int i = 0; i < FC1_IN; ++i) s += h3s[i] * fw1[i * FC1_OUT + tid];
        float v = fmaxf(s, 0.0f);
        lls[tid] = v;
        out[2 * B_GRAPHS * NUM_CLASSES + (size_t)g * FC1_OUT + tid] = v;
    }
    __syncthreads();
    if (tid < NUM_CLASSES) {
        float s = fb2[tid];
        for (int j = 0; j < FC1_OUT; ++j) s += lls[j] * fw2[j * NUM_CLASSES + tid];
        outs[tid] = s;
        out[B_GRAPHS * NUM_CLASSES + (size_t)g * NUM_CLASSES + tid] = s;
    }
    __syncthreads();
    if (tid < NUM_CLASSES) {
        float m = -INFINITY;
        for (int k2 = 0; k2 < NUM_CLASSES; ++k2) m = fmaxf(m, outs[k2]);
        float se = 0.0f;
        for (int k2 = 0; k2 < NUM_CLASSES; ++k2) se += expf(outs[k2] - m);
        out[(size_t)g * NUM_CLASSES + tid] = outs[tid] - m - logf(se);
    }
}

extern "C" void kernel_launch(void* const* d_in, const int* in_sizes, int n_in,
                              void* d_out, int out_size, void* d_ws, size_t ws_size,
                              hipStream_t stream) {
    const float* x   = (const float*)d_in[0];
    const int*   ei  = (const int*)d_in[1];
    const int*   row = ei;
    const int*   col = ei + N_EDGES;
    const int*   bat = (const int*)d_in[2];
    const float* W1  = (const float*)d_in[4];
    const float* b1  = (const float*)d_in[5];
    const float* W2  = (const float*)d_in[6];
    const float* b2  = (const float*)d_in[7];
    const float* w3  = (const float*)d_in[8];
    const float* b3  = (const float*)d_in[9];
    const float* w4  = (const float*)d_in[10];
    const float* b4  = (const float*)d_in[11];
    const float* fw1 = (const float*)d_in[12];
    const float* fb1 = (const float*)d_in[13];
    const float* fw2 = (const float*)d_in[14];
    const float* fb2 = (const float*)d_in[15];

    char* wsb = (char*)d_ws;
    unsigned short* xws = (unsigned short*)wsb;       wsb += (size_t)(N_NODES + 1) * H1C * 2; // 12.8 MB (+zero row)
    float* x1     = (float*)wsb;                      wsb += (size_t)N_NODES * H1C * 4;       // 25.6 MB
    int*   erow   = (int*)wsb;                        wsb += (size_t)NBKT * BSTRIDE * 4;      // 16.0 MB
    // ebkt aliases x1 (16.0 MB <= 25.6 MB): consumed by k_csr before k_agg1f writes x1
    unsigned int* ebkt = (unsigned int*)x1;
    int*   gcur   = (int*)wsb;                        wsb += (size_t)NBKT * 4;
    int2*  rowse  = (int2*)wsb;                       wsb += (size_t)N_NODES * 8;
    float* dis    = (float*)wsb;                      wsb += (size_t)N_NODES * 4;
    float* xws2   = (float*)wsb;                      wsb += (size_t)N_NODES * 4;
    float* outp   = (float*)d_out;

    hipMemsetAsync(gcur, 0, (size_t)NBKT * 4, stream);

    k_mscatter<<<(N_EDGES + MS_EPB - 1) / MS_EPB, 256, 0, stream>>>(row, col, gcur, ebkt);
    k_csr<<<NBKT, 256, 0, stream>>>(ebkt, gcur, dis, rowse, erow);
    k_xw1<<<(N_NODES + 63) / 64, 256, 0, stream>>>(x, W1, dis, xws);
    k_agg1f<<<(N_NODES + 3) / 4, 256, 0, stream>>>(rowse, erow, xws, dis, b1, W2, x1, xws2);
    k_poolhead<<<B_GRAPHS, 256, 0, stream>>>(bat, x1, rowse, erow, xws2, dis, b2,
                                             w3, b3, w4, b4, fw1, fb1, fw2, fb2, outp);
}